// Round 1
// baseline (35.909 us; speedup 1.0000x reference)
//
#include <hip/hip_runtime.h>
#include <math.h>

#define NQ   3
#define NV   7
#define DE   4096
#define SEQ  8192
#define NT   1024   // threads per block (16 waves)
#define NW   (NT/64)

__global__ __launch_bounds__(NT) void qhead_kernel(
    const int*   __restrict__ tok,     // (8192,)
    const float* __restrict__ embed,   // (7, 4096)
    const float* __restrict__ W,       // (3, 4096)
    const float* __restrict__ b,       // (3,)
    const float* __restrict__ wts,     // (3, 2)
    float*       __restrict__ out)     // (7,)
{
    __shared__ int   s_cnt[NV];
    __shared__ float s_part[NW][NQ * NV];

    const int tid = threadIdx.x;
    if (tid < NV) s_cnt[tid] = 0;
    __syncthreads();

    // ---- 1. token histogram (7 bins) ----
    int c[NV];
#pragma unroll
    for (int v = 0; v < NV; ++v) c[v] = 0;
    for (int i = tid; i < SEQ; i += NT) {
        int t = tok[i];
#pragma unroll
        for (int v = 0; v < NV; ++v) c[v] += (t == v) ? 1 : 0;
    }
#pragma unroll
    for (int v = 0; v < NV; ++v)
        if (c[v]) atomicAdd(&s_cnt[v], c[v]);

    // ---- 2. d[q][v] = dot(W[q], embed[v])  (21 dot products, len 4096) ----
    float acc[NQ * NV];
#pragma unroll
    for (int i = 0; i < NQ * NV; ++i) acc[i] = 0.f;

    for (int k = tid; k < DE; k += NT) {
        float wv[NQ], ev[NV];
#pragma unroll
        for (int q = 0; q < NQ; ++q) wv[q] = W[q * DE + k];
#pragma unroll
        for (int v = 0; v < NV; ++v) ev[v] = embed[v * DE + k];
#pragma unroll
        for (int q = 0; q < NQ; ++q)
#pragma unroll
            for (int v = 0; v < NV; ++v)
                acc[q * NV + v] = fmaf(wv[q], ev[v], acc[q * NV + v]);
    }

    // wave-level shuffle reduce (64 lanes)
#pragma unroll
    for (int i = 0; i < NQ * NV; ++i) {
        float x = acc[i];
        for (int off = 32; off > 0; off >>= 1) x += __shfl_down(x, off);
        acc[i] = x;
    }
    const int wave = tid >> 6, lane = tid & 63;
    if (lane == 0) {
#pragma unroll
        for (int i = 0; i < NQ * NV; ++i) s_part[wave][i] = acc[i];
    }
    __syncthreads();

    // ---- 3. finish on thread 0: angles -> 3-qubit circuit -> log-probs ----
    if (tid == 0) {
        float d[NQ * NV];
        for (int i = 0; i < NQ * NV; ++i) {
            float s = 0.f;
            for (int w = 0; w < NW; ++w) s += s_part[w][i];
            d[i] = s;
        }

        double angles[NQ];
        for (int q = 0; q < NQ; ++q) {
            double s = 0.0;
            for (int v = 0; v < NV; ++v)
                s += (double)d[q * NV + v] * (double)s_cnt[v];
            angles[q] = s / (double)SEQ + (double)b[q];
        }

        // state: 8 complex amplitudes; index = q0*4 + q1*2 + q2 (wire i -> bit 2-i)
        double sre[8], sim[8];
        for (int i = 0; i < 8; ++i) { sre[i] = 0.0; sim[i] = 0.0; }
        sre[0] = 1.0;

        auto apply1q = [&](int wire,
                           double u00r, double u00i, double u01r, double u01i,
                           double u10r, double u10i, double u11r, double u11i) {
            const int mask = 1 << (2 - wire);
            for (int idx = 0; idx < 8; ++idx) {
                if (idx & mask) continue;
                const int j = idx | mask;
                double a0r = sre[idx], a0i = sim[idx];
                double a1r = sre[j],   a1i = sim[j];
                sre[idx] = u00r * a0r - u00i * a0i + u01r * a1r - u01i * a1i;
                sim[idx] = u00r * a0i + u00i * a0r + u01r * a1i + u01i * a1r;
                sre[j]   = u10r * a0r - u10i * a0i + u11r * a1r - u11i * a1i;
                sim[j]   = u10r * a0i + u10i * a0r + u11r * a1i + u11i * a1r;
            }
        };

        // RX(angle_q) then RZ(angle_q) on each wire
        for (int q = 0; q < NQ; ++q) {
            double t  = angles[q];
            double cc = cos(t * 0.5), ss = sin(t * 0.5);
            // RX: [[c, -i s], [-i s, c]]
            apply1q(q, cc, 0.0, 0.0, -ss, 0.0, -ss, cc, 0.0);
            // RZ: [[e^{-it/2}, 0], [0, e^{+it/2}]]
            apply1q(q, cc, -ss, 0.0, 0.0, 0.0, 0.0, cc, ss);
        }

        // CNOT(0,1), CNOT(1,2)
        for (int cw = 0; cw < NQ - 1; ++cw) {
            const int cm = 1 << (2 - cw);
            const int tm = 1 << (2 - (cw + 1));
            for (int idx = 0; idx < 8; ++idx) {
                if ((idx & cm) && !(idx & tm)) {
                    const int j = idx | tm;
                    double tr = sre[idx], ti = sim[idx];
                    sre[idx] = sre[j]; sim[idx] = sim[j];
                    sre[j] = tr;       sim[j] = ti;
                }
            }
        }

        // RY(w0*angle + w1) per wire
        for (int q = 0; q < NQ; ++q) {
            double t  = (double)wts[q * 2 + 0] * angles[q] + (double)wts[q * 2 + 1];
            double cc = cos(t * 0.5), ss = sin(t * 0.5);
            // RY: [[c, -s], [s, c]]
            apply1q(q, cc, 0.0, -ss, 0.0, ss, 0.0, cc, 0.0);
        }

        for (int v = 0; v < NV; ++v) {
            double p = sre[v] * sre[v] + sim[v] * sim[v];
            out[v] = (float)log(p + 1e-9);
        }
    }
}

extern "C" void kernel_launch(void* const* d_in, const int* in_sizes, int n_in,
                              void* d_out, int out_size, void* d_ws, size_t ws_size,
                              hipStream_t stream) {
    const int*   tok   = (const int*)  d_in[0];
    const float* embed = (const float*)d_in[1];
    const float* W     = (const float*)d_in[2];
    const float* b     = (const float*)d_in[3];
    const float* wts   = (const float*)d_in[4];
    float*       out   = (float*)d_out;

    qhead_kernel<<<1, NT, 0, stream>>>(tok, embed, W, b, wts, out);
}

// Round 2
// 19.411 us; speedup vs baseline: 1.8499x; 1.8499x over previous
//
#include <hip/hip_runtime.h>
#include <math.h>

#define NQ   3
#define NV   7
#define DE   4096
#define SEQ  8192

#define NB   64            // blocks in kernel 1
#define COLS (DE / NB)     // 64 columns per block
#define TPB  (SEQ / NB)    // 128 tokens per block

// d_ws layout: [NB][21] float partial dots, then [NB][7] int partial counts
#define WS_F_CNT (NB * NQ * NV)

__global__ __launch_bounds__(64) void qhead_k1(
    const int*   __restrict__ tok,     // (8192,)
    const float* __restrict__ embed,   // (7, 4096)
    const float* __restrict__ W,       // (3, 4096)
    float*       __restrict__ ws_f,    // (NB, 21)
    int*         __restrict__ ws_i)    // (NB, 7)
{
    const int b    = blockIdx.x;
    const int lane = threadIdx.x;      // 0..63
    const int col  = b * COLS + lane;  // one column per lane

    // ---- partial dot products: acc[q][v] = W[q][col] * embed[v][col] ----
    float wv[NQ], ev[NV];
#pragma unroll
    for (int q = 0; q < NQ; ++q) wv[q] = W[q * DE + col];
#pragma unroll
    for (int v = 0; v < NV; ++v) ev[v] = embed[v * DE + col];

    float acc[NQ * NV];
#pragma unroll
    for (int q = 0; q < NQ; ++q)
#pragma unroll
        for (int v = 0; v < NV; ++v)
            acc[q * NV + v] = wv[q] * ev[v];

    // ---- partial histogram over this block's 128 tokens ----
    int c[NV];
#pragma unroll
    for (int v = 0; v < NV; ++v) c[v] = 0;
#pragma unroll
    for (int it = 0; it < TPB / 64; ++it) {
        int t = tok[b * TPB + it * 64 + lane];
#pragma unroll
        for (int v = 0; v < NV; ++v) c[v] += (t == v) ? 1 : 0;
    }

    // ---- wave-wide shuffle reduction (64 lanes), fixed order => deterministic ----
#pragma unroll
    for (int i = 0; i < NQ * NV; ++i) {
        float x = acc[i];
        for (int off = 32; off > 0; off >>= 1) x += __shfl_down(x, off);
        acc[i] = x;
    }
#pragma unroll
    for (int v = 0; v < NV; ++v) {
        int x = c[v];
        for (int off = 32; off > 0; off >>= 1) x += __shfl_down(x, off);
        c[v] = x;
    }

    if (lane == 0) {
#pragma unroll
        for (int i = 0; i < NQ * NV; ++i) ws_f[b * (NQ * NV) + i] = acc[i];
#pragma unroll
        for (int v = 0; v < NV; ++v)      ws_i[b * NV + v] = c[v];
    }
}

__global__ __launch_bounds__(64) void qhead_k2(
    const float* __restrict__ ws_f,    // (NB, 21)
    const int*   __restrict__ ws_i,    // (NB, 7)
    const float* __restrict__ b_vec,   // (3,)
    const float* __restrict__ wts,     // (3, 2)
    float*       __restrict__ out)     // (7,)
{
    __shared__ float s_d[NQ * NV];
    __shared__ int   s_c[NV];

    const int lane = threadIdx.x;

    if (lane < NQ * NV) {
        float s = 0.f;
#pragma unroll 8
        for (int blk = 0; blk < NB; ++blk) s += ws_f[blk * (NQ * NV) + lane];
        s_d[lane] = s;
    }
    if (lane < NV) {
        int s = 0;
#pragma unroll 8
        for (int blk = 0; blk < NB; ++blk) s += ws_i[blk * NV + lane];
        s_c[lane] = s;
    }
    __syncthreads();

    if (lane == 0) {
        double angles[NQ];
        for (int q = 0; q < NQ; ++q) {
            double s = 0.0;
            for (int v = 0; v < NV; ++v)
                s += (double)s_d[q * NV + v] * (double)s_c[v];
            angles[q] = s / (double)SEQ + (double)b_vec[q];
        }

        // state: 8 complex amplitudes; index = q0*4 + q1*2 + q2 (wire i -> bit 2-i)
        double sre[8], sim[8];
        for (int i = 0; i < 8; ++i) { sre[i] = 0.0; sim[i] = 0.0; }
        sre[0] = 1.0;

        auto apply1q = [&](int wire,
                           double u00r, double u00i, double u01r, double u01i,
                           double u10r, double u10i, double u11r, double u11i) {
            const int mask = 1 << (2 - wire);
            for (int idx = 0; idx < 8; ++idx) {
                if (idx & mask) continue;
                const int j = idx | mask;
                double a0r = sre[idx], a0i = sim[idx];
                double a1r = sre[j],   a1i = sim[j];
                sre[idx] = u00r * a0r - u00i * a0i + u01r * a1r - u01i * a1i;
                sim[idx] = u00r * a0i + u00i * a0r + u01r * a1i + u01i * a1r;
                sre[j]   = u10r * a0r - u10i * a0i + u11r * a1r - u11i * a1i;
                sim[j]   = u10r * a0i + u10i * a0r + u11r * a1i + u11i * a1r;
            }
        };

        // RX(angle_q) then RZ(angle_q) on each wire
        for (int q = 0; q < NQ; ++q) {
            double t  = angles[q];
            double cc = cos(t * 0.5), ss = sin(t * 0.5);
            apply1q(q, cc, 0.0, 0.0, -ss, 0.0, -ss, cc, 0.0);   // RX
            apply1q(q, cc, -ss, 0.0, 0.0, 0.0, 0.0, cc, ss);    // RZ
        }

        // CNOT(0,1), CNOT(1,2)
        for (int cw = 0; cw < NQ - 1; ++cw) {
            const int cm = 1 << (2 - cw);
            const int tm = 1 << (2 - (cw + 1));
            for (int idx = 0; idx < 8; ++idx) {
                if ((idx & cm) && !(idx & tm)) {
                    const int j = idx | tm;
                    double tr = sre[idx], ti = sim[idx];
                    sre[idx] = sre[j]; sim[idx] = sim[j];
                    sre[j] = tr;       sim[j] = ti;
                }
            }
        }

        // RY(w0*angle + w1) per wire
        for (int q = 0; q < NQ; ++q) {
            double t  = (double)wts[q * 2 + 0] * angles[q] + (double)wts[q * 2 + 1];
            double cc = cos(t * 0.5), ss = sin(t * 0.5);
            apply1q(q, cc, 0.0, -ss, 0.0, ss, 0.0, cc, 0.0);    // RY
        }

        for (int v = 0; v < NV; ++v) {
            double p = sre[v] * sre[v] + sim[v] * sim[v];
            out[v] = (float)log(p + 1e-9);
        }
    }
}

extern "C" void kernel_launch(void* const* d_in, const int* in_sizes, int n_in,
                              void* d_out, int out_size, void* d_ws, size_t ws_size,
                              hipStream_t stream) {
    const int*   tok   = (const int*)  d_in[0];
    const float* embed = (const float*)d_in[1];
    const float* W     = (const float*)d_in[2];
    const float* b     = (const float*)d_in[3];
    const float* wts   = (const float*)d_in[4];
    float*       out   = (float*)d_out;

    float* ws_f = (float*)d_ws;
    int*   ws_i = (int*)((float*)d_ws + WS_F_CNT);

    qhead_k1<<<NB, 64, 0, stream>>>(tok, embed, W, ws_f, ws_i);
    qhead_k2<<<1, 64, 0, stream>>>(ws_f, ws_i, b, wts, out);
}

// Round 3
// 15.789 us; speedup vs baseline: 2.2743x; 1.2294x over previous
//
#include <hip/hip_runtime.h>
#include <math.h>

#define NQ   3
#define NV   7
#define DE   4096
#define SEQ  8192
#define NT   1024          // one block, 16 waves on one CU
#define NW   (NT / 64)

__global__ __launch_bounds__(NT) void qhead_fused(
    const int*   __restrict__ tok,     // (8192,)
    const float* __restrict__ embed,   // (7, 4096)
    const float* __restrict__ W,       // (3, 4096)
    const float* __restrict__ bvec,    // (3,)
    const float* __restrict__ wts,     // (3, 2)
    float*       __restrict__ out)     // (7,)
{
    __shared__ float s_d[NW][NQ * NV];
    __shared__ int   s_c[NW][NV];

    const int tid  = threadIdx.x;
    const int wave = tid >> 6;
    const int lane = tid & 63;

    // ---- 1. token histogram: 8 tokens/thread via two int4 loads ----
    int c[NV];
#pragma unroll
    for (int v = 0; v < NV; ++v) c[v] = 0;
    const int4* tok4 = (const int4*)tok;           // 2048 int4
#pragma unroll
    for (int it = 0; it < 2; ++it) {
        int4 t = tok4[it * NT + tid];
#pragma unroll
        for (int v = 0; v < NV; ++v) {
            c[v] += (t.x == v) ? 1 : 0;
            c[v] += (t.y == v) ? 1 : 0;
            c[v] += (t.z == v) ? 1 : 0;
            c[v] += (t.w == v) ? 1 : 0;
        }
    }

    // ---- 2. partial dots: thread owns 4 consecutive columns (float4 loads) ----
    const float4* W4 = (const float4*)W;           // row stride 1024 float4
    const float4* E4 = (const float4*)embed;
    float4 wv[NQ], ev[NV];
#pragma unroll
    for (int q = 0; q < NQ; ++q) wv[q] = W4[q * (DE / 4) + tid];
#pragma unroll
    for (int v = 0; v < NV; ++v) ev[v] = E4[v * (DE / 4) + tid];

    float acc[NQ * NV];
#pragma unroll
    for (int q = 0; q < NQ; ++q)
#pragma unroll
        for (int v = 0; v < NV; ++v) {
            float s = wv[q].x * ev[v].x;
            s = fmaf(wv[q].y, ev[v].y, s);
            s = fmaf(wv[q].z, ev[v].z, s);
            s = fmaf(wv[q].w, ev[v].w, s);
            acc[q * NV + v] = s;
        }

    // ---- 3. wave-wide shuffle reduction (fixed order -> deterministic) ----
#pragma unroll
    for (int i = 0; i < NQ * NV; ++i) {
        float x = acc[i];
        for (int off = 32; off > 0; off >>= 1) x += __shfl_down(x, off);
        acc[i] = x;
    }
#pragma unroll
    for (int v = 0; v < NV; ++v) {
        int x = c[v];
        for (int off = 32; off > 0; off >>= 1) x += __shfl_down(x, off);
        c[v] = x;
    }
    if (lane == 0) {
#pragma unroll
        for (int i = 0; i < NQ * NV; ++i) s_d[wave][i] = acc[i];
#pragma unroll
        for (int v = 0; v < NV; ++v)      s_c[wave][v] = c[v];
    }
    __syncthreads();

    // ---- 4. cross-wave reduction by wave 0 (21 + 7 parallel lanes) ----
    if (wave == 0) {
        if (lane < NQ * NV) {
            float s = 0.f;
#pragma unroll
            for (int w = 0; w < NW; ++w) s += s_d[w][lane];
            s_d[0][lane] = s;
        }
        if (lane < NV) {
            int s = 0;
#pragma unroll
            for (int w = 0; w < NW; ++w) s += s_c[w][lane];
            s_c[0][lane] = s;
        }
    }
    __syncthreads();

    // ---- 5. serial tail on thread 0: f32 circuit with HW trig ----
    if (tid == 0) {
        float angles[NQ];
#pragma unroll
        for (int q = 0; q < NQ; ++q) {
            double s = 0.0;
#pragma unroll
            for (int v = 0; v < NV; ++v)
                s += (double)s_d[0][q * NV + v] * (double)s_c[0][v];
            angles[q] = (float)(s / (double)SEQ) + bvec[q];
        }

        // state: 8 complex amplitudes; index = q0*4 + q1*2 + q2 (wire i -> bit 2-i)
        float sre[8], sim[8];
#pragma unroll
        for (int i = 0; i < 8; ++i) { sre[i] = 0.f; sim[i] = 0.f; }
        sre[0] = 1.f;

        auto apply1q = [&](int wire,
                           float u00r, float u00i, float u01r, float u01i,
                           float u10r, float u10i, float u11r, float u11i) {
            const int mask = 1 << (2 - wire);
            for (int idx = 0; idx < 8; ++idx) {
                if (idx & mask) continue;
                const int j = idx | mask;
                float a0r = sre[idx], a0i = sim[idx];
                float a1r = sre[j],   a1i = sim[j];
                sre[idx] = u00r * a0r - u00i * a0i + u01r * a1r - u01i * a1i;
                sim[idx] = u00r * a0i + u00i * a0r + u01r * a1i + u01i * a1r;
                sre[j]   = u10r * a0r - u10i * a0i + u11r * a1r - u11i * a1i;
                sim[j]   = u10r * a0i + u10i * a0r + u11r * a1i + u11i * a1r;
            }
        };

        // RX(a) then RZ(a) per wire — share one sincos per wire
#pragma unroll
        for (int q = 0; q < NQ; ++q) {
            float ss, cc;
            __sincosf(angles[q] * 0.5f, &ss, &cc);
            apply1q(q, cc, 0.f, 0.f, -ss, 0.f, -ss, cc, 0.f);   // RX
            apply1q(q, cc, -ss, 0.f, 0.f, 0.f, 0.f, cc, ss);    // RZ
        }

        // CNOT(0,1), CNOT(1,2)
#pragma unroll
        for (int cw = 0; cw < NQ - 1; ++cw) {
            const int cm = 1 << (2 - cw);
            const int tm = 1 << (2 - (cw + 1));
            for (int idx = 0; idx < 8; ++idx) {
                if ((idx & cm) && !(idx & tm)) {
                    const int j = idx | tm;
                    float tr = sre[idx], ti = sim[idx];
                    sre[idx] = sre[j]; sim[idx] = sim[j];
                    sre[j] = tr;       sim[j] = ti;
                }
            }
        }

        // RY(w0*angle + w1) per wire
#pragma unroll
        for (int q = 0; q < NQ; ++q) {
            float t = fmaf(wts[q * 2 + 0], angles[q], wts[q * 2 + 1]);
            float ss, cc;
            __sincosf(t * 0.5f, &ss, &cc);
            apply1q(q, cc, 0.f, -ss, 0.f, ss, 0.f, cc, 0.f);    // RY
        }

#pragma unroll
        for (int v = 0; v < NV; ++v) {
            float p = sre[v] * sre[v] + sim[v] * sim[v];
            out[v] = logf(p + 1e-9f);
        }
    }
}

extern "C" void kernel_launch(void* const* d_in, const int* in_sizes, int n_in,
                              void* d_out, int out_size, void* d_ws, size_t ws_size,
                              hipStream_t stream) {
    const int*   tok   = (const int*)  d_in[0];
    const float* embed = (const float*)d_in[1];
    const float* W     = (const float*)d_in[2];
    const float* b     = (const float*)d_in[3];
    const float* wts   = (const float*)d_in[4];
    float*       out   = (float*)d_out;

    qhead_fused<<<1, NT, 0, stream>>>(tok, embed, W, b, wts, out);
}

// Round 4
// 13.172 us; speedup vs baseline: 2.7262x; 1.1987x over previous
//
#include <hip/hip_runtime.h>
#include <math.h>

#define NQ   3
#define NV   7
#define DE   4096
#define SEQ  8192
#define NB   64                 // blocks in K1 (one wave each, 64 CUs)
#define ND   (NQ * NV)          // 21 dot partials
#define NP   (ND + NV)          // + 7 count partials = 28 per block

// ws layout: float ws[NP][NB] — row i = partial i across all blocks
// (contiguous in b so K2 lane i can read its row with float4 loads)

__global__ __launch_bounds__(64) void qhead_k1(
    const int*   __restrict__ tok,     // (8192,)
    const float* __restrict__ embed,   // (7, 4096)
    const float* __restrict__ W,       // (3, 4096)
    float*       __restrict__ ws)      // (NP, NB)
{
    const int b    = blockIdx.x;
    const int lane = threadIdx.x;          // 0..63
    const int col  = b * 64 + lane;        // one embedding column per lane

    // ---- partial dots (this block owns 64 columns) ----
    float wv[NQ], ev[NV];
#pragma unroll
    for (int q = 0; q < NQ; ++q) wv[q] = W[q * DE + col];
#pragma unroll
    for (int v = 0; v < NV; ++v) ev[v] = embed[v * DE + col];

    float acc[NP];
#pragma unroll
    for (int q = 0; q < NQ; ++q)
#pragma unroll
        for (int v = 0; v < NV; ++v)
            acc[q * NV + v] = wv[q] * ev[v];

    // ---- partial histogram (this block owns 128 tokens), exact in f32 ----
    const int2 t = ((const int2*)(tok + b * 128))[lane];
#pragma unroll
    for (int v = 0; v < NV; ++v)
        acc[ND + v] = ((t.x == v) ? 1.f : 0.f) + ((t.y == v) ? 1.f : 0.f);

    // ---- wave-wide shuffle reduction (fixed order -> deterministic) ----
#pragma unroll
    for (int i = 0; i < NP; ++i) {
        float x = acc[i];
        for (int off = 32; off > 0; off >>= 1) x += __shfl_down(x, off);
        acc[i] = x;
    }

    if (lane == 0) {
#pragma unroll
        for (int i = 0; i < NP; ++i) ws[i * NB + b] = acc[i];
    }
}

__global__ __launch_bounds__(64) void qhead_k2(
    const float* __restrict__ ws,      // (NP, NB)
    const float* __restrict__ bvec,    // (3,)
    const float* __restrict__ wts,     // (3, 2)
    float*       __restrict__ out)     // (7,)
{
    __shared__ float s_all[NP];        // 21 dots + 7 counts
    __shared__ float s_ang[NQ];
    __shared__ float s_sin[6], s_cos[6];  // lanes 0-2: RX/RZ half-angles, 3-5: RY
    __shared__ float s_p[8];

    const int lane = threadIdx.x;

    // ---- 1. 28 lanes sum their partial row (16 float4 loads, pipelined) ----
    if (lane < NP) {
        const float4* p = (const float4*)(ws + lane * NB);
        float s = 0.f;
#pragma unroll
        for (int j = 0; j < NB / 4; ++j) {
            float4 v = p[j];
            s += v.x + v.y + v.z + v.w;
        }
        s_all[lane] = s;
    }
    __syncthreads();

    // ---- 2. three lanes compute angles in parallel ----
    if (lane < NQ) {
        float a = 0.f;
#pragma unroll
        for (int v = 0; v < NV; ++v)
            a = fmaf(s_all[lane * NV + v], s_all[ND + v], a);
        s_ang[lane] = a * (1.f / SEQ) + bvec[lane];
    }
    __syncthreads();

    // ---- 3. six lanes compute all sincos pairs in parallel (1 trig latency) ----
    if (lane < 6) {
        const int q = (lane < 3) ? lane : lane - 3;
        const float t = (lane < 3)
            ? s_ang[q] * 0.5f
            : fmaf(wts[q * 2 + 0], s_ang[q], wts[q * 2 + 1]) * 0.5f;
        float ss, cc;
        __sincosf(t, &ss, &cc);
        s_sin[lane] = ss;
        s_cos[lane] = cc;
    }
    __syncthreads();

    // ---- 4. lane 0: pure-FLOP gate arithmetic (trig precomputed) ----
    if (lane == 0) {
        // state: 8 complex amplitudes; index = q0*4 + q1*2 + q2 (wire i -> bit 2-i)
        float sre[8], sim[8];
#pragma unroll
        for (int i = 0; i < 8; ++i) { sre[i] = 0.f; sim[i] = 0.f; }
        sre[0] = 1.f;

        auto apply1q = [&](int wire,
                           float u00r, float u00i, float u01r, float u01i,
                           float u10r, float u10i, float u11r, float u11i) {
            const int mask = 1 << (2 - wire);
            for (int idx = 0; idx < 8; ++idx) {
                if (idx & mask) continue;
                const int j = idx | mask;
                float a0r = sre[idx], a0i = sim[idx];
                float a1r = sre[j],   a1i = sim[j];
                sre[idx] = u00r * a0r - u00i * a0i + u01r * a1r - u01i * a1i;
                sim[idx] = u00r * a0i + u00i * a0r + u01r * a1i + u01i * a1r;
                sre[j]   = u10r * a0r - u10i * a0i + u11r * a1r - u11i * a1i;
                sim[j]   = u10r * a0i + u10i * a0r + u11r * a1i + u11i * a1r;
            }
        };

        // RX(a) then RZ(a) per wire
#pragma unroll
        for (int q = 0; q < NQ; ++q) {
            const float ss = s_sin[q], cc = s_cos[q];
            apply1q(q, cc, 0.f, 0.f, -ss, 0.f, -ss, cc, 0.f);   // RX
            apply1q(q, cc, -ss, 0.f, 0.f, 0.f, 0.f, cc, ss);    // RZ
        }

        // CNOT(0,1), CNOT(1,2)
#pragma unroll
        for (int cw = 0; cw < NQ - 1; ++cw) {
            const int cm = 1 << (2 - cw);
            const int tm = 1 << (2 - (cw + 1));
            for (int idx = 0; idx < 8; ++idx) {
                if ((idx & cm) && !(idx & tm)) {
                    const int j = idx | tm;
                    float tr = sre[idx], ti = sim[idx];
                    sre[idx] = sre[j]; sim[idx] = sim[j];
                    sre[j] = tr;       sim[j] = ti;
                }
            }
        }

        // RY per wire (trig from lanes 3..5)
#pragma unroll
        for (int q = 0; q < NQ; ++q) {
            const float ss = s_sin[3 + q], cc = s_cos[3 + q];
            apply1q(q, cc, 0.f, -ss, 0.f, ss, 0.f, cc, 0.f);    // RY
        }

#pragma unroll
        for (int i = 0; i < 8; ++i)
            s_p[i] = sre[i] * sre[i] + sim[i] * sim[i];
    }
    __syncthreads();

    // ---- 5. seven lanes: parallel log + store ----
    if (lane < NV)
        out[lane] = __logf(s_p[lane] + 1e-9f);
}

extern "C" void kernel_launch(void* const* d_in, const int* in_sizes, int n_in,
                              void* d_out, int out_size, void* d_ws, size_t ws_size,
                              hipStream_t stream) {
    const int*   tok   = (const int*)  d_in[0];
    const float* embed = (const float*)d_in[1];
    const float* W     = (const float*)d_in[2];
    const float* b     = (const float*)d_in[3];
    const float* wts   = (const float*)d_in[4];
    float*       out   = (float*)d_out;
    float*       ws    = (float*)d_ws;   // NP*NB*4 = 7 KB

    qhead_k1<<<NB, 64, 0, stream>>>(tok, embed, W, ws);
    qhead_k2<<<1, 64, 0, stream>>>(ws, b, wts, out);
}

// Round 5
// 13.070 us; speedup vs baseline: 2.7474x; 1.0078x over previous
//
#include <hip/hip_runtime.h>
#include <math.h>

#define NQ   3
#define NV   7
#define DE   4096
#define SEQ  8192
#define NB   64                 // one wave per block, spread over 64 CUs
#define ND   (NQ * NV)          // 21 dot partials
#define NP   (ND + NV)          // + 7 count partials = 28 per block

// Arrival counter in module .data — NOT in d_ws/d_out, so it is never
// poisoned by the harness. Invariant: 0 at every kernel_launch boundary
// (the winner block restores it to 0 before exiting).
__device__ int g_arrive = 0;

// ws layout: float ws[NP][NB] — row i contiguous in b so winner lane i
// reads its row with float4 loads.

__global__ __launch_bounds__(64) void qhead_onepass(
    const int*   __restrict__ tok,     // (8192,)
    const float* __restrict__ embed,   // (7, 4096)
    const float* __restrict__ W,       // (3, 4096)
    const float* __restrict__ bvec,    // (3,)
    const float* __restrict__ wts,     // (3, 2)
    float*       __restrict__ ws,      // (NP, NB) in d_ws
    float*       __restrict__ out)     // (7,)
{
    __shared__ float s_all[NP];
    __shared__ float s_ang[NQ];
    __shared__ float s_sin[6], s_cos[6];
    __shared__ float s_p[8];
    __shared__ int   s_win;

    const int b    = blockIdx.x;
    const int lane = threadIdx.x;          // 0..63
    const int col  = b * 64 + lane;        // one embedding column per lane

    // ---- phase 1: per-block partials (3 KB of global reads per block) ----
    float wv[NQ], ev[NV];
#pragma unroll
    for (int q = 0; q < NQ; ++q) wv[q] = W[q * DE + col];
#pragma unroll
    for (int v = 0; v < NV; ++v) ev[v] = embed[v * DE + col];

    float acc[NP];
#pragma unroll
    for (int q = 0; q < NQ; ++q)
#pragma unroll
        for (int v = 0; v < NV; ++v)
            acc[q * NV + v] = wv[q] * ev[v];

    // 128 tokens per block, 2 per lane, exact small-int counts in f32
    const int2 t = ((const int2*)(tok + b * 128))[lane];
#pragma unroll
    for (int v = 0; v < NV; ++v)
        acc[ND + v] = ((t.x == v) ? 1.f : 0.f) + ((t.y == v) ? 1.f : 0.f);

    // wave-wide shuffle reduction (fixed order -> deterministic)
#pragma unroll
    for (int i = 0; i < NP; ++i) {
        float x = acc[i];
        for (int off = 32; off > 0; off >>= 1) x += __shfl_down(x, off);
        acc[i] = x;
    }

    // ---- arrival: release partials, count in; last block continues ----
    if (lane == 0) {
#pragma unroll
        for (int i = 0; i < NP; ++i) ws[i * NB + b] = acc[i];
        __threadfence();                       // release (cross-XCD visible)
        const int old = atomicAdd(&g_arrive, 1);
        s_win = (old == NB - 1) ? 1 : 0;
    }
    __syncthreads();
    if (!s_win) return;                        // 63 blocks exit; no spinning

    __threadfence();                           // acquire: invalidate stale L2

    // ---- phase 2 (winner block only): finish ----
    // 28 lanes sum their partial row (16 float4 loads, pipelined)
    if (lane < NP) {
        const float4* p = (const float4*)(ws + lane * NB);
        float s = 0.f;
#pragma unroll
        for (int j = 0; j < NB / 4; ++j) {
            float4 v = p[j];
            s += v.x + v.y + v.z + v.w;
        }
        s_all[lane] = s;
    }
    __syncthreads();

    // three lanes compute angles in parallel
    if (lane < NQ) {
        float a = 0.f;
#pragma unroll
        for (int v = 0; v < NV; ++v)
            a = fmaf(s_all[lane * NV + v], s_all[ND + v], a);
        s_ang[lane] = a * (1.f / SEQ) + bvec[lane];
    }
    __syncthreads();

    // six lanes compute all sincos pairs concurrently (one trig latency)
    if (lane < 6) {
        const int q = (lane < 3) ? lane : lane - 3;
        const float th = (lane < 3)
            ? s_ang[q] * 0.5f
            : fmaf(wts[q * 2 + 0], s_ang[q], wts[q * 2 + 1]) * 0.5f;
        float ss, cc;
        __sincosf(th, &ss, &cc);
        s_sin[lane] = ss;
        s_cos[lane] = cc;
    }
    __syncthreads();

    // lane 0: pure-FLOP gate arithmetic (trig precomputed)
    if (lane == 0) {
        // state: 8 complex amplitudes; index = q0*4 + q1*2 + q2 (wire i -> bit 2-i)
        float sre[8], sim[8];
#pragma unroll
        for (int i = 0; i < 8; ++i) { sre[i] = 0.f; sim[i] = 0.f; }
        sre[0] = 1.f;

        auto apply1q = [&](int wire,
                           float u00r, float u00i, float u01r, float u01i,
                           float u10r, float u10i, float u11r, float u11i) {
            const int mask = 1 << (2 - wire);
            for (int idx = 0; idx < 8; ++idx) {
                if (idx & mask) continue;
                const int j = idx | mask;
                float a0r = sre[idx], a0i = sim[idx];
                float a1r = sre[j],   a1i = sim[j];
                sre[idx] = u00r * a0r - u00i * a0i + u01r * a1r - u01i * a1i;
                sim[idx] = u00r * a0i + u00i * a0r + u01r * a1i + u01i * a1r;
                sre[j]   = u10r * a0r - u10i * a0i + u11r * a1r - u11i * a1i;
                sim[j]   = u10r * a0i + u10i * a0r + u11r * a1i + u11i * a1r;
            }
        };

        // RX(a) then RZ(a) per wire
#pragma unroll
        for (int q = 0; q < NQ; ++q) {
            const float ss = s_sin[q], cc = s_cos[q];
            apply1q(q, cc, 0.f, 0.f, -ss, 0.f, -ss, cc, 0.f);   // RX
            apply1q(q, cc, -ss, 0.f, 0.f, 0.f, 0.f, cc, ss);    // RZ
        }

        // CNOT(0,1), CNOT(1,2)
#pragma unroll
        for (int cw = 0; cw < NQ - 1; ++cw) {
            const int cm = 1 << (2 - cw);
            const int tm = 1 << (2 - (cw + 1));
            for (int idx = 0; idx < 8; ++idx) {
                if ((idx & cm) && !(idx & tm)) {
                    const int j = idx | tm;
                    float tr = sre[idx], ti = sim[idx];
                    sre[idx] = sre[j]; sim[idx] = sim[j];
                    sre[j] = tr;       sim[j] = ti;
                }
            }
        }

        // RY per wire (trig from lanes 3..5)
#pragma unroll
        for (int q = 0; q < NQ; ++q) {
            const float ss = s_sin[3 + q], cc = s_cos[3 + q];
            apply1q(q, cc, 0.f, -ss, 0.f, ss, 0.f, cc, 0.f);    // RY
        }

#pragma unroll
        for (int i = 0; i < 8; ++i)
            s_p[i] = sre[i] * sre[i] + sim[i] * sim[i];
    }
    __syncthreads();

    // seven lanes: parallel log + store; lane 63 restores the counter
    if (lane < NV)
        out[lane] = __logf(s_p[lane] + 1e-9f);
    if (lane == 63)
        g_arrive = 0;    // back to the call-boundary invariant
}

extern "C" void kernel_launch(void* const* d_in, const int* in_sizes, int n_in,
                              void* d_out, int out_size, void* d_ws, size_t ws_size,
                              hipStream_t stream) {
    const int*   tok   = (const int*)  d_in[0];
    const float* embed = (const float*)d_in[1];
    const float* W     = (const float*)d_in[2];
    const float* b     = (const float*)d_in[3];
    const float* wts   = (const float*)d_in[4];
    float*       out   = (float*)d_out;
    float*       ws    = (float*)d_ws;   // NP*NB*4 = 7 KB

    qhead_onepass<<<NB, 64, 0, stream>>>(tok, embed, W, b, wts, ws, out);
}